// Round 10
// baseline (222.867 us; speedup 1.0000x reference)
//
#include <hip/hip_runtime.h>
#include <math.h>

typedef unsigned int u32;
typedef unsigned long long u64;
typedef unsigned short u16;

#define NN 50000
#define NE 800000
#define TOPK 8
#define SCAN_B 196            // ceil(50000/256)
#define AGG_B 2048            // agg grid: 8 blocks/CU * 4 waves = 32 waves/CU

__device__ __forceinline__ u64 shflxor64(u64 v, int m) {
    int lo = __shfl_xor((int)(u32)v, m);
    int hi = __shfl_xor((int)(u32)(v >> 32), m);
    return ((u64)(u32)hi << 32) | (u32)lo;
}
// f32 -> bf16 bits, round-to-nearest-even (inputs finite)
__device__ __forceinline__ u32 f2bf(float v) {
    u32 u = __float_as_uint(v);
    return (u + 0x7FFFu + ((u >> 16) & 1u)) >> 16;
}
__device__ __forceinline__ float bf2f(u16 b) {
    return __uint_as_float(((u32)b) << 16);
}
__device__ __forceinline__ u32 sortable(float v) {
    u32 b = __float_as_uint(v);
    return (b & 0x80000000u) ? ~b : (b | 0x80000000u);
}

// ---------------- h = x @ W + fused s_i/s_j ----------------
// BM=64 rows/block (782 blocks -> ~3 blocks/CU), BK=64 two chunks.
// x staged k-major with XOR swizzle: xst[k][r ^ 4*((k>>2)&7)] — staging
// writes hit 32 distinct banks (2-way alias only = free), compute reads
// remain 16B-aligned b128 (swizzle is bits 2-4; i bits 0-1 untouched).
// LDS 48 KB -> 3 blocks/CU. Summation order (k ascending, 2 chunks)
// identical to previous round -> s_i/s_j bit-identical -> same selection.
__global__ __launch_bounds__(256) void gemm_k(const float* __restrict__ x,
                                              const float* __restrict__ W,
                                              const float* __restrict__ att,
                                              u16* __restrict__ hbuf,
                                              float* __restrict__ s_i,
                                              float* __restrict__ s_j) {
    __shared__ float xst[64 * 64];    // [k][r swizzled], 16 KB
    __shared__ float ws[64][128];     // [k][c], 32 KB
    const int t = threadIdx.x;
    const int cx = t & 15;            // col group: cols cx*8..+7
    const int ry = t >> 4;            // row group: rows ry*4..+3
    const int rbase = blockIdx.x * 64;

    float acc[4][8];
    #pragma unroll
    for (int i = 0; i < 4; ++i)
        #pragma unroll
        for (int j = 0; j < 8; ++j) acc[i][j] = 0.f;

    for (int kk = 0; kk < 128; kk += 64) {
        if (kk) __syncthreads();
        // stage x: thread loads x[rbase + ry + 16s][kk + cx*4 .. +3] (coalesced),
        // writes 4 scalars to swizzled k-major tile. k-group = cx -> swz = 4*(cx&7).
        const int xoff = 4 * (cx & 7);
        #pragma unroll
        for (int s = 0; s < 4; ++s) {
            int r = ry + 16 * s;
            int gr = rbase + r;
            float4 v = make_float4(0.f, 0.f, 0.f, 0.f);
            if (gr < NN)
                v = *reinterpret_cast<const float4*>(x + (size_t)gr * 128 + kk + cx * 4);
            int rw = r ^ xoff;
            xst[(cx * 4 + 0) * 64 + rw] = v.x;
            xst[(cx * 4 + 1) * 64 + rw] = v.y;
            xst[(cx * 4 + 2) * 64 + rw] = v.z;
            xst[(cx * 4 + 3) * 64 + rw] = v.w;
        }
        // stage W rows kk..kk+63 (coalesced full rows)
        #pragma unroll
        for (int wk = t >> 5; wk < 64; wk += 8) {
            float4 v = *reinterpret_cast<const float4*>(W + (size_t)(kk + wk) * 128 + (t & 31) * 4);
            *reinterpret_cast<float4*>(&ws[wk][(t & 31) * 4]) = v;
        }
        __syncthreads();

        #pragma unroll
        for (int k = 0; k < 64; ++k) {
            const int swz = 4 * ((k >> 2) & 7);
            float4 xa = *reinterpret_cast<const float4*>(&xst[k * 64 + ((ry * 4) ^ swz)]);
            float4 wa = *reinterpret_cast<const float4*>(&ws[k][cx * 8]);
            float4 wb = *reinterpret_cast<const float4*>(&ws[k][cx * 8 + 4]);
            float xv[4] = {xa.x, xa.y, xa.z, xa.w};
            float wv[8] = {wa.x, wa.y, wa.z, wa.w, wb.x, wb.y, wb.z, wb.w};
            #pragma unroll
            for (int i = 0; i < 4; ++i)
                #pragma unroll
                for (int j = 0; j < 8; ++j) acc[i][j] += xv[i] * wv[j];
        }
    }

    // epilogue: store h (bf16) + fused s_i/s_j (f32)
    const int head = cx >> 2;
    float aiv[8], ajv[8];
    #pragma unroll
    for (int j = 0; j < 8; ++j) {
        aiv[j] = att[head * 64 + (cx & 3) * 8 + j];
        ajv[j] = att[head * 64 + 32 + (cx & 3) * 8 + j];
    }
    #pragma unroll
    for (int i = 0; i < 4; ++i) {
        int gr = rbase + ry * 4 + i;
        float pi = 0.f, pj = 0.f;
        #pragma unroll
        for (int j = 0; j < 8; ++j) {
            pi += acc[i][j] * aiv[j];
            pj += acc[i][j] * ajv[j];
        }
        pi += __shfl_xor(pi, 1); pi += __shfl_xor(pi, 2);
        pj += __shfl_xor(pj, 1); pj += __shfl_xor(pj, 2);
        if (gr < NN) {
            uint4 pk;
            pk.x = f2bf(acc[i][0]) | (f2bf(acc[i][1]) << 16);
            pk.y = f2bf(acc[i][2]) | (f2bf(acc[i][3]) << 16);
            pk.z = f2bf(acc[i][4]) | (f2bf(acc[i][5]) << 16);
            pk.w = f2bf(acc[i][6]) | (f2bf(acc[i][7]) << 16);
            *reinterpret_cast<uint4*>(hbuf + (size_t)gr * 128 + cx * 8) = pk;
            if ((cx & 3) == 0) {
                s_i[(size_t)gr * 4 + head] = pi;
                s_j[(size_t)gr * 4 + head] = pj;
            }
        }
    }
}

// ---------------- degree + per-edge rank (atomic return), x4 ----------------
__global__ __launch_bounds__(256) void deg_k(const int* __restrict__ ei,
                                             int* __restrict__ deg,
                                             int* __restrict__ rank) {
    int e4 = (blockIdx.x * 256 + threadIdx.x) * 4;
    if (e4 >= NE) return;
    int4 v = *reinterpret_cast<const int4*>(ei + e4);
    int4 r;
    r.x = atomicAdd(deg + v.x, 1);
    r.y = atomicAdd(deg + v.y, 1);
    r.z = atomicAdd(deg + v.z, 1);
    r.w = atomicAdd(deg + v.w, 1);
    *reinterpret_cast<int4*>(rank + e4) = r;
}

// ---------------- scan stage 1: per-block scan of deg[i] ----------------
__global__ __launch_bounds__(256) void scan1_k(const int* __restrict__ deg,
                                               int* __restrict__ offs,
                                               int* __restrict__ bsum) {
    const int t = threadIdx.x;
    const int lane = t & 63, wid = t >> 6;
    const int i = blockIdx.x * 256 + t;
    int val = (i < NN) ? deg[i] : 0;
    int v = val;
    #pragma unroll
    for (int off = 1; off < 64; off <<= 1) {
        int o = __shfl_up(v, off);
        if (lane >= off) v += o;
    }
    __shared__ int wsum[4], wpre[4];
    if (lane == 63) wsum[wid] = v;
    __syncthreads();
    if (t == 0) {
        int acc = 0;
        #pragma unroll
        for (int w = 0; w < 4; ++w) { wpre[w] = acc; acc += wsum[w]; }
        bsum[blockIdx.x] = acc;
    }
    __syncthreads();
    if (i < NN) offs[i] = v - val + wpre[wid];   // exclusive within block
}

// ---------------- scan stage 2+3 fused: block prefix + final offs ----------------
__global__ __launch_bounds__(256) void scan3_k(const int* __restrict__ bsum,
                                               int* __restrict__ offs) {
    const int t = threadIdx.x;
    const int b = blockIdx.x;
    const int lane = t & 63, wid = t >> 6;
    int v = (t < b) ? bsum[t] : 0;
    #pragma unroll
    for (int off = 1; off < 64; off <<= 1) v += __shfl_xor(v, off);
    __shared__ int wsum[4];
    __shared__ int pre;
    if (lane == 0) wsum[wid] = v;
    __syncthreads();
    if (t == 0) pre = wsum[0] + wsum[1] + wsum[2] + wsum[3];
    __syncthreads();
    const int i = b * 256 + t;
    if (i < NN) offs[i] += pre;
    if (b == 0 && t == 0) offs[NN] = NE;
}

// ---------------- CSR scatter: col only (4 B), no atomic ----------------
__global__ __launch_bounds__(256) void scatter_k(const int* __restrict__ ei,
                                                 const int* __restrict__ rank,
                                                 const int* __restrict__ offs,
                                                 int* __restrict__ ccol) {
    int e = (blockIdx.x * 256 + threadIdx.x) * 2;
    if (e >= NE) return;
    int2 rr = *reinterpret_cast<const int2*>(ei + e);
    int2 cc = *reinterpret_cast<const int2*>(ei + NE + e);
    int2 rk = *reinterpret_cast<const int2*>(rank + e);
    ccol[offs[rr.x] + rk.x] = cc.x;
    ccol[offs[rr.y] + rk.y] = cc.y;
}

// ---------------- selection: top-8 + softmax -> packed (alpha,col) ----------------
// 8 threads per row = 4 heads x 2 halves; key = (sortable(s_j)<<32)|col.
// Tie note: bit-equal keys only from duplicate cols in a row (identical
// value & contribution) -> eid order unnecessary.
// Merge: each lane's own mk[0..7] = {max(own[i], partner[7-i])} is the full
// top-8 multiset of the union; lane A's mk[0..3] and lane B's mk[0..3] are
// complementary within it. Each half writes ITS OWN first 4 entries.
__global__ __launch_bounds__(256) void sel_k(const int* __restrict__ offs,
                                             const int* __restrict__ ccol,
                                             const float* __restrict__ s_i,
                                             const float* __restrict__ s_j,
                                             u64* __restrict__ pal) {
    const int t = threadIdx.x;
    const int lr = t >> 3;
    const int head = (t >> 1) & 3;
    const int half = t & 1;
    const int row = blockIdx.x * 32 + lr;
    if (row >= NN) return;   // partner (t^1) shares row -> exits together

    u64 kl[TOPK];
    #pragma unroll
    for (int i = 0; i < TOPK; ++i) kl[i] = 0ull;

    const int o0 = offs[row];
    const int dg = offs[row + 1] - o0;

    if (half == 0) {   // synthetic self-loop
        u32 fk = sortable(s_j[(size_t)row * 4 + head]);
        kl[0] = ((u64)fk << 32) | (u32)row;
    }
    for (int j = half; j < dg; j += 2) {
        int col = ccol[o0 + j];
        u32 fk = sortable(s_j[(size_t)col * 4 + head]);
        u64 key = ((u64)fk << 32) | (u32)col;
        #pragma unroll
        for (int i = 0; i < TOPK; ++i) {
            bool gt = key > kl[i];
            u64 mx = gt ? key : kl[i];
            key = gt ? kl[i] : key;
            kl[i] = mx;
        }
    }

    // merge with partner: own top-8-of-union multiset (per-lane view)
    u64 mk[TOPK];
    #pragma unroll
    for (int i = 0; i < TOPK; ++i) {
        u64 pk = shflxor64(kl[TOPK - 1 - i], 1);
        mk[i] = (kl[i] >= pk) ? kl[i] : pk;
    }
    u64 pk0 = shflxor64(kl[0], 1);
    u64 mxk = (kl[0] >= pk0) ? kl[0] : pk0;   // global max (kl[0] = half max)

    const float si = s_i[(size_t)row * 4 + head];
    u32 fk = (u32)(mxk >> 32);
    u32 mb = (fk & 0x80000000u) ? (fk ^ 0x80000000u) : ~fk;
    float em = si + __uint_as_float(mb);
    float m = (em >= 0.f) ? em : 0.2f * em;

    float al[TOPK];
    float denom = 0.f;
    #pragma unroll
    for (int i = 0; i < TOPK; ++i) {
        u32 fki = (u32)(mk[i] >> 32);
        u32 bi = (fki & 0x80000000u) ? (fki ^ 0x80000000u) : ~fki;
        float e = si + __uint_as_float(bi);
        e = (e >= 0.f) ? e : 0.2f * e;
        float z = (mk[i] != 0ull) ? __expf(e - m) : 0.f;
        al[i] = z;
        denom += z;
    }
    float inv = 1.f / denom;

    // each half writes its OWN mk[0..3]/al[0..3] to slots half*4..half*4+3
    u64* dst = pal + ((size_t)row * 4 + head) * 8;
    #pragma unroll
    for (int i = 0; i < 4; ++i) {
        dst[half * 4 + i] = ((u64)__float_as_uint(al[i] * inv) << 32) | (u32)mk[i];
    }
}

// ---------------- aggregation: weighted gather + ELU ----------------
// grid-stride: one wave per row per iteration; lanes = 32 ch x 2 halves.
// bf16 h gathers (64 B line per pick); pal reads uniform per half.
__global__ __launch_bounds__(256) void agg_k(const u64* __restrict__ pal,
                                             const u16* __restrict__ hbuf,
                                             float* __restrict__ out) {
    const int t = threadIdx.x;
    const int lane = t & 63;
    const int c = lane & 31, hw = lane >> 5;
    const int w0 = blockIdx.x * 4 + (t >> 6);
    const int stride = AGG_B * 4;

    for (int r = w0; r < NN; r += stride) {
        #pragma unroll
        for (int hh = 0; hh < 4; ++hh) {
            const u64* p = pal + ((size_t)r * 4 + hh) * 8;
            float acc = 0.f;
            #pragma unroll
            for (int k2 = hw; k2 < TOPK; k2 += 2) {
                u64 pr = p[k2];
                float a = __uint_as_float((u32)(pr >> 32));
                int col = (int)(u32)pr;
                acc += a * bf2f(hbuf[(size_t)col * 128 + hh * 32 + c]);
            }
            acc += __shfl_xor(acc, 32);
            if (hw == 0) {
                float o = acc;
                o = (o > 0.f) ? o : expm1f(o);   // ELU
                out[(size_t)r * 128 + hh * 32 + c] = o;
            }
        }
    }
}

extern "C" void kernel_launch(void* const* d_in, const int* in_sizes, int n_in,
                              void* d_out, int out_size, void* d_ws, size_t ws_size,
                              hipStream_t stream) {
    const float* x   = (const float*)d_in[0];   // 50000x128 f32
    const float* W   = (const float*)d_in[1];   // 128x128  f32
    const float* att = (const float*)d_in[2];   // 4x64     f32
    const int*   ei  = (const int*)d_in[3];     // 2x800000 int32
    float* out = (float*)d_out;                 // 50000x128 f32

    u64* pal     = (u64*)d_ws;                  // 1.6M u64 (12.8 MB, 8-aligned)
    u16* hbuf    = (u16*)(pal + (size_t)NN * 4 * 8);  // 6.4M bf16 (12.8 MB)
    float* s_i   = (float*)(hbuf + (size_t)NN * 128); // 200k f32
    float* s_j   = s_i + NN * 4;                // 200k f32
    int* deg     = (int*)(s_j + NN * 4);        // 50k
    int* offs    = deg + NN;                    // 50001
    int* rank    = offs + NN + 1;               // 800k
    int* ccol    = rank + NE;                   // 800k
    int* bsum    = ccol + NE;                   // 196
    // total ws: ~34 MB

    hipMemsetAsync(deg, 0, NN * sizeof(int), stream);
    gemm_k<<<(NN + 63) / 64, 256, 0, stream>>>(x, W, att, hbuf, s_i, s_j);
    deg_k<<<(NE / 4 + 255) / 256, 256, 0, stream>>>(ei, deg, rank);
    scan1_k<<<SCAN_B, 256, 0, stream>>>(deg, offs, bsum);
    scan3_k<<<SCAN_B, 256, 0, stream>>>(bsum, offs);
    scatter_k<<<(NE / 2 + 255) / 256, 256, 0, stream>>>(ei, rank, offs, ccol);
    sel_k<<<(NN + 31) / 32, 256, 0, stream>>>(offs, ccol, s_i, s_j, pal);
    agg_k<<<AGG_B, 256, 0, stream>>>(pal, hbuf, out);
}

// Round 11
// 217.172 us; speedup vs baseline: 1.0262x; 1.0262x over previous
//
#include <hip/hip_runtime.h>
#include <math.h>

typedef unsigned int u32;
typedef unsigned long long u64;
typedef unsigned short u16;

#define NN 50000
#define NE 800000
#define TOPK 8
#define SCAN_B 196            // ceil(50000/256)
#define AGG_B 2048            // agg grid: 8 blocks/CU * 4 waves = 32 waves/CU

__device__ __forceinline__ u64 shflxor64(u64 v, int m) {
    int lo = __shfl_xor((int)(u32)v, m);
    int hi = __shfl_xor((int)(u32)(v >> 32), m);
    return ((u64)(u32)hi << 32) | (u32)lo;
}
// f32 -> bf16 bits, round-to-nearest-even (inputs finite)
__device__ __forceinline__ u32 f2bf(float v) {
    u32 u = __float_as_uint(v);
    return (u + 0x7FFFu + ((u >> 16) & 1u)) >> 16;
}
__device__ __forceinline__ float bf2f(u16 b) {
    return __uint_as_float(((u32)b) << 16);
}
__device__ __forceinline__ u32 sortable(float v) {
    u32 b = __float_as_uint(v);
    return (b & 0x80000000u) ? ~b : (b | 0x80000000u);
}

// ---------------- h = x @ W + fused s_i/s_j ----------------
// BM=32 rows/block -> 1563 blocks (~6 blocks/CU, grid-limited concurrency 2x
// round 10). BK=32, 4 chunks, LDS 20 KB. Thread map: cx=t>>4 (8 cols),
// ry=t&15 (2 rows) -> per wave only 4 col-groups (16-lane broadcast W reads,
// conflict-free) and 16 row-groups (x reads conflict-free). One wave = one
// head. k ascending 0..127 with carried acc -> s_i/s_j bit-identical to
// previous rounds -> same top-k selection.
__global__ __launch_bounds__(256) void gemm_k(const float* __restrict__ x,
                                              const float* __restrict__ W,
                                              const float* __restrict__ att,
                                              u16* __restrict__ hbuf,
                                              float* __restrict__ s_i,
                                              float* __restrict__ s_j) {
    __shared__ float xst[32 * 32];    // [k][r ^ swz], 4 KB
    __shared__ float ws[32 * 128];    // [k][c] row-major chunk, 16 KB
    const int t = threadIdx.x;
    const int cx = t >> 4;            // col group: cols cx*8..+7 (wave = head)
    const int ry = t & 15;            // row group: rows ry*2..+1
    const int rbase = blockIdx.x * 32;

    float acc[2][8];
    #pragma unroll
    for (int i = 0; i < 2; ++i)
        #pragma unroll
        for (int j = 0; j < 8; ++j) acc[i][j] = 0.f;

    for (int kk = 0; kk < 128; kk += 32) {
        if (kk) __syncthreads();
        // stage x: thread r=t>>3 (32 rows), kq=t&7 (4 floats) — coalesced.
        // write swizzled k-major: xst[k][r ^ 4*kq]  (2-way max, free)
        {
            int r = t >> 3, kq = t & 7;
            int gr = rbase + r;
            float4 v = make_float4(0.f, 0.f, 0.f, 0.f);
            if (gr < NN)
                v = *reinterpret_cast<const float4*>(x + (size_t)gr * 128 + kk + kq * 4);
            int rw = r ^ (4 * kq);       // swz(k)=4*((k>>2)&7)=4*kq for k=kq*4+q
            xst[(kq * 4 + 0) * 32 + rw] = v.x;
            xst[(kq * 4 + 1) * 32 + rw] = v.y;
            xst[(kq * 4 + 2) * 32 + rw] = v.z;
            xst[(kq * 4 + 3) * 32 + rw] = v.w;
        }
        // stage W chunk (32x128) as linear contiguous copy — coalesced
        {
            const float* wsrc = W + (size_t)kk * 128;
            #pragma unroll
            for (int i = 0; i < 4; ++i) {
                float4 v = *reinterpret_cast<const float4*>(wsrc + i * 1024 + t * 4);
                *reinterpret_cast<float4*>(&ws[i * 1024 + t * 4]) = v;
            }
        }
        __syncthreads();

        #pragma unroll
        for (int k = 0; k < 32; ++k) {
            const int swz = 4 * ((k >> 2) & 7);
            float2 xa = *reinterpret_cast<const float2*>(&xst[k * 32 + ((ry * 2) ^ swz)]);
            float4 wa = *reinterpret_cast<const float4*>(&ws[k * 128 + cx * 8]);
            float4 wb = *reinterpret_cast<const float4*>(&ws[k * 128 + cx * 8 + 4]);
            float xv[2] = {xa.x, xa.y};
            float wv[8] = {wa.x, wa.y, wa.z, wa.w, wb.x, wb.y, wb.z, wb.w};
            #pragma unroll
            for (int i = 0; i < 2; ++i)
                #pragma unroll
                for (int j = 0; j < 8; ++j) acc[i][j] += xv[i] * wv[j];
        }
    }

    // epilogue: store h (bf16) + fused s_i/s_j (f32)
    // threads for (row-group, head): lanes (cx&3)*16 + ry -> shfl 16, 32
    const int head = cx >> 2;         // == t>>6 (wave id)
    float aiv[8], ajv[8];
    #pragma unroll
    for (int j = 0; j < 8; ++j) {
        aiv[j] = att[head * 64 + (cx & 3) * 8 + j];
        ajv[j] = att[head * 64 + 32 + (cx & 3) * 8 + j];
    }
    #pragma unroll
    for (int i = 0; i < 2; ++i) {
        int gr = rbase + ry * 2 + i;
        float pi = 0.f, pj = 0.f;
        #pragma unroll
        for (int j = 0; j < 8; ++j) {
            pi += acc[i][j] * aiv[j];
            pj += acc[i][j] * ajv[j];
        }
        pi += __shfl_xor(pi, 16); pi += __shfl_xor(pi, 32);
        pj += __shfl_xor(pj, 16); pj += __shfl_xor(pj, 32);
        if (gr < NN) {
            uint4 pk;
            pk.x = f2bf(acc[i][0]) | (f2bf(acc[i][1]) << 16);
            pk.y = f2bf(acc[i][2]) | (f2bf(acc[i][3]) << 16);
            pk.z = f2bf(acc[i][4]) | (f2bf(acc[i][5]) << 16);
            pk.w = f2bf(acc[i][6]) | (f2bf(acc[i][7]) << 16);
            *reinterpret_cast<uint4*>(hbuf + (size_t)gr * 128 + cx * 8) = pk;
            if ((cx & 3) == 0) {
                s_i[(size_t)gr * 4 + head] = pi;
                s_j[(size_t)gr * 4 + head] = pj;
            }
        }
    }
}

// ---------------- degree + per-edge rank (atomic return), x4 ----------------
__global__ __launch_bounds__(256) void deg_k(const int* __restrict__ ei,
                                             int* __restrict__ deg,
                                             int* __restrict__ rank) {
    int e4 = (blockIdx.x * 256 + threadIdx.x) * 4;
    if (e4 >= NE) return;
    int4 v = *reinterpret_cast<const int4*>(ei + e4);
    int4 r;
    r.x = atomicAdd(deg + v.x, 1);
    r.y = atomicAdd(deg + v.y, 1);
    r.z = atomicAdd(deg + v.z, 1);
    r.w = atomicAdd(deg + v.w, 1);
    *reinterpret_cast<int4*>(rank + e4) = r;
}

// ---------------- scan stage 1: per-block scan of deg[i] ----------------
__global__ __launch_bounds__(256) void scan1_k(const int* __restrict__ deg,
                                               int* __restrict__ offs,
                                               int* __restrict__ bsum) {
    const int t = threadIdx.x;
    const int lane = t & 63, wid = t >> 6;
    const int i = blockIdx.x * 256 + t;
    int val = (i < NN) ? deg[i] : 0;
    int v = val;
    #pragma unroll
    for (int off = 1; off < 64; off <<= 1) {
        int o = __shfl_up(v, off);
        if (lane >= off) v += o;
    }
    __shared__ int wsum[4], wpre[4];
    if (lane == 63) wsum[wid] = v;
    __syncthreads();
    if (t == 0) {
        int acc = 0;
        #pragma unroll
        for (int w = 0; w < 4; ++w) { wpre[w] = acc; acc += wsum[w]; }
        bsum[blockIdx.x] = acc;
    }
    __syncthreads();
    if (i < NN) offs[i] = v - val + wpre[wid];   // exclusive within block
}

// ---------------- scan stage 2+3 fused: block prefix + final offs ----------------
__global__ __launch_bounds__(256) void scan3_k(const int* __restrict__ bsum,
                                               int* __restrict__ offs) {
    const int t = threadIdx.x;
    const int b = blockIdx.x;
    const int lane = t & 63, wid = t >> 6;
    int v = (t < b) ? bsum[t] : 0;
    #pragma unroll
    for (int off = 1; off < 64; off <<= 1) v += __shfl_xor(v, off);
    __shared__ int wsum[4];
    __shared__ int pre;
    if (lane == 0) wsum[wid] = v;
    __syncthreads();
    if (t == 0) pre = wsum[0] + wsum[1] + wsum[2] + wsum[3];
    __syncthreads();
    const int i = b * 256 + t;
    if (i < NN) offs[i] += pre;
    if (b == 0 && t == 0) offs[NN] = NE;
}

// ---------------- CSR scatter: col only (4 B), no atomic ----------------
__global__ __launch_bounds__(256) void scatter_k(const int* __restrict__ ei,
                                                 const int* __restrict__ rank,
                                                 const int* __restrict__ offs,
                                                 int* __restrict__ ccol) {
    int e = (blockIdx.x * 256 + threadIdx.x) * 2;
    if (e >= NE) return;
    int2 rr = *reinterpret_cast<const int2*>(ei + e);
    int2 cc = *reinterpret_cast<const int2*>(ei + NE + e);
    int2 rk = *reinterpret_cast<const int2*>(rank + e);
    ccol[offs[rr.x] + rk.x] = cc.x;
    ccol[offs[rr.y] + rk.y] = cc.y;
}

// ---------------- selection: top-8 + softmax -> packed (alpha,col) ----------------
// 8 threads per row = 4 heads x 2 halves; key = (sortable(s_j)<<32)|col.
// Tie note: bit-equal keys only from duplicate cols in a row (identical
// value & contribution) -> eid order unnecessary.
// Merge: each lane's own mk[0..7] = {max(own[i], partner[7-i])} is the full
// top-8 multiset of the union; lane A's mk[0..3] and lane B's mk[0..3] are
// complementary within it. Each half writes ITS OWN first 4 entries.
__global__ __launch_bounds__(256) void sel_k(const int* __restrict__ offs,
                                             const int* __restrict__ ccol,
                                             const float* __restrict__ s_i,
                                             const float* __restrict__ s_j,
                                             u64* __restrict__ pal) {
    const int t = threadIdx.x;
    const int lr = t >> 3;
    const int head = (t >> 1) & 3;
    const int half = t & 1;
    const int row = blockIdx.x * 32 + lr;
    if (row >= NN) return;   // partner (t^1) shares row -> exits together

    u64 kl[TOPK];
    #pragma unroll
    for (int i = 0; i < TOPK; ++i) kl[i] = 0ull;

    const int o0 = offs[row];
    const int dg = offs[row + 1] - o0;

    if (half == 0) {   // synthetic self-loop
        u32 fk = sortable(s_j[(size_t)row * 4 + head]);
        kl[0] = ((u64)fk << 32) | (u32)row;
    }
    for (int j = half; j < dg; j += 2) {
        int col = ccol[o0 + j];
        u32 fk = sortable(s_j[(size_t)col * 4 + head]);
        u64 key = ((u64)fk << 32) | (u32)col;
        #pragma unroll
        for (int i = 0; i < TOPK; ++i) {
            bool gt = key > kl[i];
            u64 mx = gt ? key : kl[i];
            key = gt ? kl[i] : key;
            kl[i] = mx;
        }
    }

    // merge with partner: own top-8-of-union multiset (per-lane view)
    u64 mk[TOPK];
    #pragma unroll
    for (int i = 0; i < TOPK; ++i) {
        u64 pk = shflxor64(kl[TOPK - 1 - i], 1);
        mk[i] = (kl[i] >= pk) ? kl[i] : pk;
    }
    u64 pk0 = shflxor64(kl[0], 1);
    u64 mxk = (kl[0] >= pk0) ? kl[0] : pk0;   // global max (kl[0] = half max)

    const float si = s_i[(size_t)row * 4 + head];
    u32 fk = (u32)(mxk >> 32);
    u32 mb = (fk & 0x80000000u) ? (fk ^ 0x80000000u) : ~fk;
    float em = si + __uint_as_float(mb);
    float m = (em >= 0.f) ? em : 0.2f * em;

    float al[TOPK];
    float denom = 0.f;
    #pragma unroll
    for (int i = 0; i < TOPK; ++i) {
        u32 fki = (u32)(mk[i] >> 32);
        u32 bi = (fki & 0x80000000u) ? (fki ^ 0x80000000u) : ~fki;
        float e = si + __uint_as_float(bi);
        e = (e >= 0.f) ? e : 0.2f * e;
        float z = (mk[i] != 0ull) ? __expf(e - m) : 0.f;
        al[i] = z;
        denom += z;
    }
    float inv = 1.f / denom;

    // each half writes its OWN mk[0..3]/al[0..3] to slots half*4..half*4+3
    u64* dst = pal + ((size_t)row * 4 + head) * 8;
    #pragma unroll
    for (int i = 0; i < 4; ++i) {
        dst[half * 4 + i] = ((u64)__float_as_uint(al[i] * inv) << 32) | (u32)mk[i];
    }
}

// ---------------- aggregation: weighted gather + ELU ----------------
// grid-stride: one wave per row per iteration; lanes = 32 ch x 2 halves.
// bf16 h gathers (64 B line per pick); pal reads uniform per half.
__global__ __launch_bounds__(256) void agg_k(const u64* __restrict__ pal,
                                             const u16* __restrict__ hbuf,
                                             float* __restrict__ out) {
    const int t = threadIdx.x;
    const int lane = t & 63;
    const int c = lane & 31, hw = lane >> 5;
    const int w0 = blockIdx.x * 4 + (t >> 6);
    const int stride = AGG_B * 4;

    for (int r = w0; r < NN; r += stride) {
        #pragma unroll
        for (int hh = 0; hh < 4; ++hh) {
            const u64* p = pal + ((size_t)r * 4 + hh) * 8;
            float acc = 0.f;
            #pragma unroll
            for (int k2 = hw; k2 < TOPK; k2 += 2) {
                u64 pr = p[k2];
                float a = __uint_as_float((u32)(pr >> 32));
                int col = (int)(u32)pr;
                acc += a * bf2f(hbuf[(size_t)col * 128 + hh * 32 + c]);
            }
            acc += __shfl_xor(acc, 32);
            if (hw == 0) {
                float o = acc;
                o = (o > 0.f) ? o : expm1f(o);   // ELU
                out[(size_t)r * 128 + hh * 32 + c] = o;
            }
        }
    }
}

extern "C" void kernel_launch(void* const* d_in, const int* in_sizes, int n_in,
                              void* d_out, int out_size, void* d_ws, size_t ws_size,
                              hipStream_t stream) {
    const float* x   = (const float*)d_in[0];   // 50000x128 f32
    const float* W   = (const float*)d_in[1];   // 128x128  f32
    const float* att = (const float*)d_in[2];   // 4x64     f32
    const int*   ei  = (const int*)d_in[3];     // 2x800000 int32
    float* out = (float*)d_out;                 // 50000x128 f32

    u64* pal     = (u64*)d_ws;                  // 1.6M u64 (12.8 MB, 8-aligned)
    u16* hbuf    = (u16*)(pal + (size_t)NN * 4 * 8);  // 6.4M bf16 (12.8 MB)
    float* s_i   = (float*)(hbuf + (size_t)NN * 128); // 200k f32
    float* s_j   = s_i + NN * 4;                // 200k f32
    int* deg     = (int*)(s_j + NN * 4);        // 50k
    int* offs    = deg + NN;                    // 50001
    int* rank    = offs + NN + 1;               // 800k
    int* ccol    = rank + NE;                   // 800k
    int* bsum    = ccol + NE;                   // 196
    // total ws: ~34 MB

    hipMemsetAsync(deg, 0, NN * sizeof(int), stream);
    gemm_k<<<(NN + 31) / 32, 256, 0, stream>>>(x, W, att, hbuf, s_i, s_j);
    deg_k<<<(NE / 4 + 255) / 256, 256, 0, stream>>>(ei, deg, rank);
    scan1_k<<<SCAN_B, 256, 0, stream>>>(deg, offs, bsum);
    scan3_k<<<SCAN_B, 256, 0, stream>>>(bsum, offs);
    scatter_k<<<(NE / 2 + 255) / 256, 256, 0, stream>>>(ei, rank, offs, ccol);
    sel_k<<<(NN + 31) / 32, 256, 0, stream>>>(offs, ccol, s_i, s_j, pal);
    agg_k<<<AGG_B, 256, 0, stream>>>(pal, hbuf, out);
}